// Round 10
// baseline (236.944 us; speedup 1.0000x reference)
//
#include <hip/hip_runtime.h>

// LightGCN propagation: 3x SpMM over fixed COO graph + batched dot epilogue.
// R23: part critical-path shortening (build = ~125us of 236, the target).
// (1) src/vals PREFETCHED in pass 1 (static regs beside d_c/r_c): pass
//     1.5 becomes pure LDS -- removes one global-latency phase from the
//     8-barrier serial path.
// (2) conv folded into each sort block as a TAIL SLICE (512 x 4688
//     float4) instead of 2344 trailing grid blocks: round-1 blocks' conv
//     overlaps round-2 blocks' latency-bound (BW-idle) sort phases; only
//     the final ~2.5us slice stays exposed (was ~12us serial).
// R22: batch+dot fused (one wave per pair, cross-half shfl); p4f single-
// atomic-pass (returning hist rank -> atomic-free iperm). R20: part
// CHUNKS=512 (2 blocks/CU), p4f coalesced write-back via LDS inverse
// permutation. R18: part = LDS counting sort, coalesced run write-out,
// padded gcur. spmm (R16): 8 nodes/wave octets, cooperative 64B epair
// fetch, 8-deep row-gather MLP; at the ~3.5TB/s random-128B-gather
// fabric ceiling (FETCH = 8 XCD x ~81% table, compulsory).
// Layer 3 batch-only (R10). bf16 rows (R5).

#define N_USERS 50000
#define N_ITEMS 100000
#define N_NODES 150000
#define N_EDGES 2400000
#define DIM 64
#define BATCH 4096

#define CHUNKS 512
#define CHUNK_EDGES 4688   // 512*4688 = 2400256 >= N_EDGES (tail guarded)
#define PPT 5              // ceil(4688/1024) edges per thread per pass
#define KB 256             // super-buckets
#define NPB 586            // nodes per bucket; 256*586 = 150016 >= N_NODES
#define ECAP 10240         // bucket capacity: mean 9375, sigma 97 -> +8.9 sigma
#define MAXIT 10           // ECAP/1024 strided iterations in p4f
#define GSTR 16            // gcur stride: 1 counter per 64B line
#define NF4 2400000        // N_NODES*DIM/4 float4 conv elements

typedef unsigned int uint;
typedef float v2f __attribute__((ext_vector_type(2)));

__device__ __forceinline__ uint pack_bf16(float a, float b) {
    uint ua = __float_as_uint(a), ub = __float_as_uint(b);
    ua = (ua + 0x7FFFu + ((ua >> 16) & 1u)) >> 16;   // RTNE
    ub = (ub + 0x7FFFu + ((ub >> 16) & 1u)) >> 16;
    return ua | (ub << 16);
}

__device__ __forceinline__ v2f unpack_bf16x2(uint w) {
    v2f r;
    r.x = __uint_as_float(w << 16);
    r.y = __uint_as_float(w & 0xFFFF0000u);
    return r;
}

// PART: LDS counting sort of the chunk's edges by super-bucket (src/vals
// prefetched in pass 1), coalesced segment write-out into reserved fat
// runs, then a per-block fp32->bf16 conv tail slice. 2 blocks/CU.
__global__ __launch_bounds__(1024) void part_kernel(
        const int* __restrict__ src, const int* __restrict__ dstA,
        const float* __restrict__ vals, int* __restrict__ gcur,
        int2* __restrict__ coarse,
        const float* __restrict__ emb_user, const float* __restrict__ emb_item,
        uint2* __restrict__ t0) {
    int t = threadIdx.x;
    __shared__ int2 stage[CHUNK_EDGES];              // 37504 B sorted payload
    __shared__ unsigned char stage_b[CHUNK_EDGES];   // 4688 B bucket ids
    __shared__ int h[KB];
    __shared__ int hoff[KB];
    __shared__ int delta[KB];
    __shared__ int wsum4[4];
    int c = blockIdx.x;
    if (t < KB) h[t] = 0;
    __syncthreads();
    int base = c * CHUNK_EDGES;
    int ecnt = min(CHUNK_EDGES, N_EDGES - base);     // tail chunk short
    int d_c[PPT];
    int r_c[PPT];
    int s_c[PPT];
    int v_c[PPT];
#pragma unroll
    for (int u = 0; u < PPT; ++u) {
        int i = t + u * 1024;
        d_c[u] = 0;
        r_c[u] = 0;
        s_c[u] = 0;
        v_c[u] = 0;
        if (i < ecnt) {
            int d = dstA[base + i];
            s_c[u] = src[base + i];                  // prefetch: pass 1.5
            v_c[u] = ((const int*)vals)[base + i];   //   becomes pure LDS
            d_c[u] = d;
            // returning atomic: rank within (chunk,bucket); independent ->
            // pipelined across the unrolled iterations.
            r_c[u] = atomicAdd(&h[(int)((unsigned)d / NPB)], 1);
        }
    }
    __syncthreads();
    int lane = t & 63, wid = t >> 6;
    if (t < KB) {                     // 4-wave scan of 256 bucket counts
        int v = h[t];
        int incl = v;
#pragma unroll
        for (int o = 1; o < 64; o <<= 1) {
            int add = __shfl_up(incl, o, 64);
            if (lane >= o) incl += add;
        }
        hoff[t] = incl - v;
        if (lane == 63) wsum4[wid] = incl;
    }
    __syncthreads();
    if (t < 64) {
        int vv = (lane < 4) ? wsum4[lane] : 0;
        int inc2 = vv;
#pragma unroll
        for (int o = 1; o < 4; o <<= 1) {
            int add = __shfl_up(inc2, o, 64);
            if (lane >= o) inc2 += add;
        }
        if (lane < 4) wsum4[lane] = inc2 - vv;
    }
    __syncthreads();
    if (t < KB) {
        int off = hoff[t] + wsum4[t >> 6];           // chunk-local bucket start
        hoff[t] = off;
        int cb = atomicAdd(&gcur[t * GSTR], h[t]);   // reserve fat run (padded)
        delta[t] = t * ECAP + cb - off;              // sorted-pos -> coarse idx
    }
    __syncthreads();
    // pass 1.5: stage edges into sorted LDS slots (pure LDS now)
#pragma unroll
    for (int u = 0; u < PPT; ++u) {
        int i = t + u * 1024;
        if (i < ecnt) {
            int d = d_c[u];
            int b = (int)((unsigned)d / NPB);
            int dl = d - b * NPB;
            int pos = hoff[b] + r_c[u];
            stage[pos] = make_int2(s_c[u] | (dl << 18), v_c[u]);
            stage_b[pos] = (unsigned char)b;
        }
    }
    __syncthreads();
    // pass 2: coalesced write-out (consecutive j -> consecutive coarse idx
    // within each per-bucket run of ~18 edges)
#pragma unroll
    for (int u = 0; u < PPT; ++u) {
        int j = t + u * 1024;
        if (j < ecnt) {
            int b = stage_b[j];
            int idx = j + delta[b];
            if (idx < (b + 1) * ECAP)                // overflow guard
                coarse[idx] = stage[j];
        }
    }
    // conv tail slice: fp32 -> bf16 concat t0. Overlaps other blocks'
    // latency-bound sort phases (BW otherwise idle). No sync needed.
    const int userN4 = N_USERS * DIM / 4;            // 800000
    int cbase = c * CHUNK_EDGES;                     // 4688 float4 per block
#pragma unroll
    for (int u = 0; u < PPT; ++u) {
        int i = cbase + t + u * 1024;
        if (i < NF4) {
            float4 v;
            if (i < userN4) v = ((const float4*)emb_user)[i];
            else            v = ((const float4*)emb_item)[i - userN4];
            t0[i] = make_uint2(pack_bf16(v.x, v.y), pack_bf16(v.z, v.w));
        }
    }
}

// P4F: per-super-bucket fine sort IN PLACE -- edges -> LDS, RETURNING-
// atomic hist (rank in regs), wave-shuffle scan, rowinfo emit,
// atomic-free inverse permutation, coalesced write-back.
__global__ __launch_bounds__(1024) void p4f_fine(int2* __restrict__ coarse,
                                                 const int* __restrict__ gcur,
                                                 uint* __restrict__ rowinfo) {
    __shared__ int2 eds[ECAP];              // 81920 B
    __shared__ unsigned short iperm[ECAP];  // 20480 B
    __shared__ int cnt[640];
    __shared__ int rs_[640];
    __shared__ int wsum[16];
    int k = blockIdx.x, t = threadIdx.x;
    int rbase = k * ECAP;
    int ne = min(gcur[k * GSTR], ECAP);
    for (int i = t; i < ne; i += 1024) eds[i] = coarse[rbase + i];
    if (t < 640) cnt[t] = 0;
    __syncthreads();
    int rr[MAXIT];
#pragma unroll
    for (int u = 0; u < MAXIT; ++u) {
        int i = t + u * 1024;
        rr[u] = 0;
        if (i < ne)
            rr[u] = atomicAdd(&cnt[eds[i].x >> 18], 1);   // returning: rank
    }
    __syncthreads();
    int wid = t >> 6, lane = t & 63;
    if (t < 640) {                    // waves 0..9 (640 = 10*64)
        int v = cnt[t];
        int incl = v;
#pragma unroll
        for (int o = 1; o < 64; o <<= 1) {
            int add = __shfl_up(incl, o, 64);
            if (lane >= o) incl += add;
        }
        rs_[t] = incl - v;
        if (lane == 63) wsum[wid] = incl;
    }
    __syncthreads();
    if (t < 64) {
        int vv = (lane < 10) ? wsum[lane] : 0;
        int inc2 = vv;
#pragma unroll
        for (int o = 1; o < 16; o <<= 1) {
            int add = __shfl_up(inc2, o, 64);
            if (lane >= o) inc2 += add;
        }
        if (lane < 10) wsum[lane] = inc2 - vv;
    }
    __syncthreads();
    if (t < 640) rs_[t] += wsum[wid];
    __syncthreads();
    int nodes0 = k * NPB;
    int nb = min(NPB, N_NODES - nodes0);
    if (t < nb)
        rowinfo[nodes0 + t] = (uint)(rbase + rs_[t]) | ((uint)cnt[t] << 22);
    // atomic-free inverse permutation: iperm[sorted_pos] = source index
#pragma unroll
    for (int u = 0; u < MAXIT; ++u) {
        int i = t + u * 1024;
        if (i < ne) {
            int dl = eds[i].x >> 18;
            iperm[rs_[dl] + rr[u]] = (unsigned short)i;
        }
    }
    __syncthreads();
    // coalesced write-back: consecutive threads -> consecutive coarse slots
    for (int j = t; j < ne; j += 1024) {
        int2 ev = eds[iperm[j]];
        coarse[rbase + j] = make_int2(ev.x & 0x3FFFF, ev.y);   // strip dl
    }
}

// SpMM over bf16 rows (128B/row). R16 form: 8 nodes per wave, one octet
// (8 lanes x uint4 = full row) per node. Per round: octet cooperatively
// loads 8 epair entries (64B coalesced), shfl-broadcasts src/val, issues
// 8 independent row gathers, then FMAs. No cross-lane reduce; wave
// stores 1KB contiguous (8 rows).
__global__ __launch_bounds__(256) void spmm_kernel(
        const uint* __restrict__ rowinfo, const int2* __restrict__ epair,
        const uint* __restrict__ xin, uint* __restrict__ xout) {
    int wave = (blockIdx.x * 256 + threadIdx.x) >> 6;
    int lane = threadIdx.x & 63;
    int g = lane >> 3;                // octet id = node slot 0..7
    int l = lane & 7;                 // uint4 slot within row
    int n = wave * 8 + g;
    bool live = n < N_NODES;
    uint ri = live ? rowinfo[n] : 0u;
    int s = (int)(ri & 0x3FFFFFu);
    int e = live ? s + (int)(ri >> 22) : s;   // empty/dead: e==s skips loop
    int gbase = g * 8;
    v2f a0 = {0.f, 0.f}, a1 = {0.f, 0.f}, a2 = {0.f, 0.f}, a3 = {0.f, 0.f};
    for (int jb = s; jb < e; jb += 8) {
        int jl = jb + l;
        // cooperative 64B epair fetch; tail clamps to e-1 (same line, w=0)
        int2 ev = epair[jl < e ? jl : (e - 1)];
        float vw = (jl < e) ? __int_as_float(ev.y) : 0.f;
        int sx = ev.x;
        int srcs[8];
        float ws[8];
#pragma unroll
        for (int u = 0; u < 8; ++u) {
            srcs[u] = __shfl(sx, gbase + u, 64);
            ws[u]   = __shfl(vw, gbase + u, 64);
        }
        uint4 r[8];
#pragma unroll
        for (int u = 0; u < 8; ++u)
            r[u] = ((const uint4*)(xin + (size_t)srcs[u] * 32))[l];
#pragma unroll
        for (int u = 0; u < 8; ++u) {
            a0 += ws[u] * unpack_bf16x2(r[u].x);
            a1 += ws[u] * unpack_bf16x2(r[u].y);
            a2 += ws[u] * unpack_bf16x2(r[u].z);
            a3 += ws[u] * unpack_bf16x2(r[u].w);
        }
    }
    if (live) {
        uint4 o;
        o.x = pack_bf16(a0.x, a0.y);
        o.y = pack_bf16(a1.x, a1.y);
        o.z = pack_bf16(a2.x, a2.y);
        o.w = pack_bf16(a3.x, a3.y);
        ((uint4*)(xout + (size_t)n * 32))[l] = o;   // wave: 8 rows = 1KB contig
    }
}

// Layer 3 + dot, fused: one wave per (user,item) pair. Half-wave per
// node (lanes 0-31 user, 32-63 item); within a half, 2 edge-groups x 16
// lanes; each lane owns dims 4l..4l+3 (uint2 slot l). After the x3
// gather: reduce across edge-groups (xor 16), add x0+x1+x2, cross-half
// shfl_xor(32) brings the partner row, in-wave dot, lane 0 writes gamma.
__global__ __launch_bounds__(256) void batch_dot_kernel(
        const int* __restrict__ users, const int* __restrict__ items,
        const float* __restrict__ emb_user, const float* __restrict__ emb_item,
        const uint* __restrict__ x1, const uint* __restrict__ x2,
        const uint* __restrict__ rowinfo, const int2* __restrict__ epair,
        float* __restrict__ out) {
    int b = (blockIdx.x * 256 + threadIdx.x) >> 6;   // 0..BATCH-1
    int lane = threadIdx.x & 63;
    int hg = (lane >> 4) & 1;  // edge-group within half
    int l = lane & 15;         // uint2 slot: dims 4l..4l+3
    bool isU = lane < 32;
    int idx = isU ? users[b] : items[b];
    int n = isU ? idx : N_USERS + idx;
    uint ri = rowinfo[n];
    int s = (int)(ri & 0x3FFFFFu);
    int e = s + (int)(ri >> 22);
    v2f a0 = {0.f, 0.f}, a1 = {0.f, 0.f};
    for (int j0 = s + hg; j0 < e; j0 += 8) {
        int2 ev[4];
        float vv[4];
        uint2 rr[4];
#pragma unroll
        for (int u = 0; u < 4; ++u) {
            int j = j0 + 2 * u;
            bool p = (u == 0) || (j < e);
            ev[u] = epair[p ? j : j0];
            vv[u] = p ? __int_as_float(ev[u].y) : 0.f;
        }
#pragma unroll
        for (int u = 0; u < 4; ++u)
            rr[u] = ((const uint2*)(x2 + (size_t)ev[u].x * 32))[l];
#pragma unroll
        for (int u = 0; u < 4; ++u) {
            a0 += vv[u] * unpack_bf16x2(rr[u].x);
            a1 += vv[u] * unpack_bf16x2(rr[u].y);
        }
    }
    // reduce across the 2 edge-groups (stays within each half)
    a0.x += __shfl_xor(a0.x, 16, 64);
    a0.y += __shfl_xor(a0.y, 16, 64);
    a1.x += __shfl_xor(a1.x, 16, 64);
    a1.y += __shfl_xor(a1.y, 16, 64);
    // epilogue: r = x0 + x1 + x2 + x3 for this node's dims 4l..4l+3
    const float* t0row = isU ? (emb_user + (size_t)idx * DIM)
                             : (emb_item + (size_t)idx * DIM);
    float4 x0 = ((const float4*)t0row)[l];
    uint2 w1 = ((const uint2*)(x1 + (size_t)n * 32))[l];
    uint2 w2 = ((const uint2*)(x2 + (size_t)n * 32))[l];
    v2f b10 = unpack_bf16x2(w1.x), b11 = unpack_bf16x2(w1.y);
    v2f b20 = unpack_bf16x2(w2.x), b21 = unpack_bf16x2(w2.y);
    float rx = x0.x + b10.x + b20.x + a0.x;
    float ry = x0.y + b10.y + b20.y + a0.y;
    float rz = x0.z + b11.x + b21.x + a1.x;
    float rw = x0.w + b11.y + b21.y + a1.y;
    // cross-half: partner row's same dims
    float ox = __shfl_xor(rx, 32, 64);
    float oy = __shfl_xor(ry, 32, 64);
    float oz = __shfl_xor(rz, 32, 64);
    float ow = __shfl_xor(rw, 32, 64);
    float p = rx * ox + ry * oy + rz * oz + rw * ow;
#pragma unroll
    for (int o = 1; o < 16; o <<= 1) p += __shfl_xor(p, o, 64);
    if (lane == 0) out[b] = p * (1.0f / 16.0f);
}

extern "C" void kernel_launch(void* const* d_in, const int* in_sizes, int n_in,
                              void* d_out, int out_size, void* d_ws, size_t ws_size,
                              hipStream_t stream) {
    const float* emb_user = (const float*)d_in[0];
    const float* emb_item = (const float*)d_in[1];
    const float* vals     = (const float*)d_in[2];
    const int*   src      = (const int*)d_in[3];
    const int*   dst      = (const int*)d_in[4];
    const int*   users    = (const int*)d_in[5];
    const int*   items    = (const int*)d_in[6];
    float* out = (float*)d_out;

    char* ws = (char*)d_ws;
    size_t off = 0;
    auto walloc = [&](size_t bytes) -> void* {
        void* p = ws + off;
        off += (bytes + 255) & ~(size_t)255;
        return p;
    };
    const size_t ROWB = (size_t)N_NODES * DIM * 2;                  // 19.2 MB
    uint* t0          = (uint*)walloc(ROWB);                        // bf16 x0
    uint* x1          = (uint*)walloc(ROWB);
    uint* x2          = (uint*)walloc(ROWB);
    int2* coarse      = (int2*)walloc((size_t)KB * ECAP * 8);       // 21.0 MB
    int*  gcur        = (int*) walloc((size_t)KB * GSTR * 4);       // padded
    uint* rowinfo     = (uint*)walloc((size_t)N_NODES * 4);

    hipMemsetAsync(gcur, 0, (size_t)KB * GSTR * 4, stream);

    // Build: partition sort (+ per-block conv tail slice), then fine sort
    part_kernel<<<CHUNKS, 1024, 0, stream>>>(
        src, dst, vals, gcur, coarse, emb_user, emb_item, (uint2*)t0);
    p4f_fine<<<KB, 1024, 0, stream>>>(coarse, gcur, rowinfo);

    // Layers 1,2 full; layer 3 + dot fused, batch-only
    const int SPMM_BLOCKS = (N_NODES / 8 * 64 + 255) / 256;
    spmm_kernel<<<SPMM_BLOCKS, 256, 0, stream>>>(rowinfo, coarse, t0, x1);
    spmm_kernel<<<SPMM_BLOCKS, 256, 0, stream>>>(rowinfo, coarse, x1, x2);
    batch_dot_kernel<<<(BATCH * 64) / 256, 256, 0, stream>>>(
        users, items, emb_user, emb_item, x1, x2, rowinfo, coarse, out);
}

// Round 11
// 230.314 us; speedup vs baseline: 1.0288x; 1.0288x over previous
//
#include <hip/hip_runtime.h>

// LightGCN propagation: 3x SpMM over fixed COO graph + batched dot epilogue.
// R24: p4f FUSED with spmm layer 1. R21-R23 micro-fixes to the build
// phase were neutral -- the dispatch boundary itself is the cost: p4f
// sorts the bucket's edges in LDS, writes 19.2MB back, then spmm1
// re-reads the same 21MB through rowinfo. Now one block per bucket:
// single-pass sort (R22 returning-rank + atomic-free iperm) -> rowinfo
// emit -> sorted write-back (fire-and-forget stores, overlap what
// follows) -> R16 octet spmm for the bucket's own 586 nodes, epair read
// from LDS via iperm (octet-broadcast, no global epair, no serial
// epair->gather chain), t0 rows gathered from global, x1 written as one
// contiguous 75KB segment. 105KB LDS -> 1 block/CU, 16 waves: 128
// gather-lines in flight/CU (vs spmm's ~160) -- enough for the ~3.5TB/s
// random-gather fabric ceiling.
// part (R23): LDS counting sort per chunk, src/vals prefetched, conv
// tail slice, 2 blocks/CU, padded gcur. spmm layer 2 (R16): 8 nodes/wave
// octets, cooperative 64B epair fetch, 8-deep row-gather MLP, at the
// fabric ceiling (FETCH = 8 XCD x ~81% table, compulsory).
// batch+dot fused (R22). Layer 3 batch-only (R10). bf16 rows (R5).

#define N_USERS 50000
#define N_ITEMS 100000
#define N_NODES 150000
#define N_EDGES 2400000
#define DIM 64
#define BATCH 4096

#define CHUNKS 512
#define CHUNK_EDGES 4688   // 512*4688 = 2400256 >= N_EDGES (tail guarded)
#define PPT 5              // ceil(4688/1024) edges per thread per pass
#define KB 256             // super-buckets
#define NPB 586            // nodes per bucket; 256*586 = 150016 >= N_NODES
#define ECAP 10240         // bucket capacity: mean 9375, sigma 97 -> +8.9 sigma
#define MAXIT 10           // ECAP/1024 strided iterations in p4f
#define GSTR 16            // gcur stride: 1 counter per 64B line
#define NF4 2400000        // N_NODES*DIM/4 float4 conv elements

typedef unsigned int uint;
typedef float v2f __attribute__((ext_vector_type(2)));

__device__ __forceinline__ uint pack_bf16(float a, float b) {
    uint ua = __float_as_uint(a), ub = __float_as_uint(b);
    ua = (ua + 0x7FFFu + ((ua >> 16) & 1u)) >> 16;   // RTNE
    ub = (ub + 0x7FFFu + ((ub >> 16) & 1u)) >> 16;
    return ua | (ub << 16);
}

__device__ __forceinline__ v2f unpack_bf16x2(uint w) {
    v2f r;
    r.x = __uint_as_float(w << 16);
    r.y = __uint_as_float(w & 0xFFFF0000u);
    return r;
}

// PART: LDS counting sort of the chunk's edges by super-bucket (src/vals
// prefetched in pass 1), coalesced segment write-out into reserved fat
// runs, then a per-block fp32->bf16 conv tail slice. 2 blocks/CU.
__global__ __launch_bounds__(1024) void part_kernel(
        const int* __restrict__ src, const int* __restrict__ dstA,
        const float* __restrict__ vals, int* __restrict__ gcur,
        int2* __restrict__ coarse,
        const float* __restrict__ emb_user, const float* __restrict__ emb_item,
        uint2* __restrict__ t0) {
    int t = threadIdx.x;
    __shared__ int2 stage[CHUNK_EDGES];              // 37504 B sorted payload
    __shared__ unsigned char stage_b[CHUNK_EDGES];   // 4688 B bucket ids
    __shared__ int h[KB];
    __shared__ int hoff[KB];
    __shared__ int delta[KB];
    __shared__ int wsum4[4];
    int c = blockIdx.x;
    if (t < KB) h[t] = 0;
    __syncthreads();
    int base = c * CHUNK_EDGES;
    int ecnt = min(CHUNK_EDGES, N_EDGES - base);     // tail chunk short
    int d_c[PPT];
    int r_c[PPT];
    int s_c[PPT];
    int v_c[PPT];
#pragma unroll
    for (int u = 0; u < PPT; ++u) {
        int i = t + u * 1024;
        d_c[u] = 0;
        r_c[u] = 0;
        s_c[u] = 0;
        v_c[u] = 0;
        if (i < ecnt) {
            int d = dstA[base + i];
            s_c[u] = src[base + i];                  // prefetch: pass 1.5
            v_c[u] = ((const int*)vals)[base + i];   //   becomes pure LDS
            d_c[u] = d;
            r_c[u] = atomicAdd(&h[(int)((unsigned)d / NPB)], 1);
        }
    }
    __syncthreads();
    int lane = t & 63, wid = t >> 6;
    if (t < KB) {                     // 4-wave scan of 256 bucket counts
        int v = h[t];
        int incl = v;
#pragma unroll
        for (int o = 1; o < 64; o <<= 1) {
            int add = __shfl_up(incl, o, 64);
            if (lane >= o) incl += add;
        }
        hoff[t] = incl - v;
        if (lane == 63) wsum4[wid] = incl;
    }
    __syncthreads();
    if (t < 64) {
        int vv = (lane < 4) ? wsum4[lane] : 0;
        int inc2 = vv;
#pragma unroll
        for (int o = 1; o < 4; o <<= 1) {
            int add = __shfl_up(inc2, o, 64);
            if (lane >= o) inc2 += add;
        }
        if (lane < 4) wsum4[lane] = inc2 - vv;
    }
    __syncthreads();
    if (t < KB) {
        int off = hoff[t] + wsum4[t >> 6];           // chunk-local bucket start
        hoff[t] = off;
        int cb = atomicAdd(&gcur[t * GSTR], h[t]);   // reserve fat run (padded)
        delta[t] = t * ECAP + cb - off;              // sorted-pos -> coarse idx
    }
    __syncthreads();
    // pass 1.5: stage edges into sorted LDS slots (pure LDS)
#pragma unroll
    for (int u = 0; u < PPT; ++u) {
        int i = t + u * 1024;
        if (i < ecnt) {
            int d = d_c[u];
            int b = (int)((unsigned)d / NPB);
            int dl = d - b * NPB;
            int pos = hoff[b] + r_c[u];
            stage[pos] = make_int2(s_c[u] | (dl << 18), v_c[u]);
            stage_b[pos] = (unsigned char)b;
        }
    }
    __syncthreads();
    // pass 2: coalesced write-out
#pragma unroll
    for (int u = 0; u < PPT; ++u) {
        int j = t + u * 1024;
        if (j < ecnt) {
            int b = stage_b[j];
            int idx = j + delta[b];
            if (idx < (b + 1) * ECAP)                // overflow guard
                coarse[idx] = stage[j];
        }
    }
    // conv tail slice: fp32 -> bf16 concat t0 (overlaps other blocks)
    const int userN4 = N_USERS * DIM / 4;            // 800000
    int cbase = c * CHUNK_EDGES;
#pragma unroll
    for (int u = 0; u < PPT; ++u) {
        int i = cbase + t + u * 1024;
        if (i < NF4) {
            float4 v;
            if (i < userN4) v = ((const float4*)emb_user)[i];
            else            v = ((const float4*)emb_item)[i - userN4];
            t0[i] = make_uint2(pack_bf16(v.x, v.y), pack_bf16(v.z, v.w));
        }
    }
}

// P4F+SPMM1 fused: per super-bucket -- edges -> LDS, returning-atomic
// hist, scan, rowinfo, atomic-free iperm, sorted write-back (for layer
// 2 / batch), then layer-1 spmm for the bucket's own nodes with epair
// served from LDS via iperm (octet-broadcast).
__global__ __launch_bounds__(1024) void p4f_spmm(
        int2* __restrict__ coarse, const int* __restrict__ gcur,
        uint* __restrict__ rowinfo,
        const uint* __restrict__ xin, uint* __restrict__ xout) {
    __shared__ int2 eds[ECAP];              // 81920 B (keeps dl bits)
    __shared__ unsigned short iperm[ECAP];  // 20480 B
    __shared__ int cnt[640];
    __shared__ int rs_[640];
    __shared__ int wsum[16];
    int k = blockIdx.x, t = threadIdx.x;
    int rbase = k * ECAP;
    int ne = min(gcur[k * GSTR], ECAP);
    for (int i = t; i < ne; i += 1024) eds[i] = coarse[rbase + i];
    if (t < 640) cnt[t] = 0;
    __syncthreads();
    int rr[MAXIT];
#pragma unroll
    for (int u = 0; u < MAXIT; ++u) {
        int i = t + u * 1024;
        rr[u] = 0;
        if (i < ne)
            rr[u] = atomicAdd(&cnt[eds[i].x >> 18], 1);   // returning: rank
    }
    __syncthreads();
    int wid = t >> 6, lane = t & 63;
    if (t < 640) {                    // waves 0..9 (640 = 10*64)
        int v = cnt[t];
        int incl = v;
#pragma unroll
        for (int o = 1; o < 64; o <<= 1) {
            int add = __shfl_up(incl, o, 64);
            if (lane >= o) incl += add;
        }
        rs_[t] = incl - v;
        if (lane == 63) wsum[wid] = incl;
    }
    __syncthreads();
    if (t < 64) {
        int vv = (lane < 10) ? wsum[lane] : 0;
        int inc2 = vv;
#pragma unroll
        for (int o = 1; o < 16; o <<= 1) {
            int add = __shfl_up(inc2, o, 64);
            if (lane >= o) inc2 += add;
        }
        if (lane < 10) wsum[lane] = inc2 - vv;
    }
    __syncthreads();
    if (t < 640) rs_[t] += wsum[wid];
    __syncthreads();
    int nodes0 = k * NPB;
    int nb = min(NPB, N_NODES - nodes0);
    if (t < nb)
        rowinfo[nodes0 + t] = (uint)(rbase + rs_[t]) | ((uint)cnt[t] << 22);
    // atomic-free inverse permutation: iperm[sorted_pos] = source index
#pragma unroll
    for (int u = 0; u < MAXIT; ++u) {
        int i = t + u * 1024;
        if (i < ne) {
            int dl = eds[i].x >> 18;
            iperm[rs_[dl] + rr[u]] = (unsigned short)i;
        }
    }
    __syncthreads();
    // sorted write-back for layer 2 / batch (fire-and-forget stores,
    // overlap the spmm gathers below)
    for (int j = t; j < ne; j += 1024) {
        int2 ev = eds[iperm[j]];
        coarse[rbase + j] = make_int2(ev.x & 0x3FFFF, ev.y);   // strip dl
    }
    // layer-1 spmm for this bucket's nodes: 16 waves x 8-node octets,
    // epair from LDS via iperm (octet-broadcast), rows gathered global.
    int wave = t >> 6;                // 0..15
    int g = lane >> 3;                // octet id within wave
    int l = lane & 7;                 // uint4 slot within row
    for (int dl0 = 0; dl0 < NPB; dl0 += 128) {   // 5 passes (586/128)
        int dl = dl0 + wave * 8 + g;
        bool live = dl < nb;
        int s = live ? rs_[dl] : 0;
        int e = live ? s + cnt[dl] : 0;
        v2f a0 = {0.f, 0.f}, a1 = {0.f, 0.f}, a2 = {0.f, 0.f}, a3 = {0.f, 0.f};
        for (int jb = s; jb < e; jb += 8) {
            int idxs[8];
#pragma unroll
            for (int u = 0; u < 8; ++u) {
                int j = jb + u;
                idxs[u] = iperm[j < e ? j : (e - 1)];
            }
            int2 ev[8];
#pragma unroll
            for (int u = 0; u < 8; ++u) ev[u] = eds[idxs[u]];
            uint4 r[8];
#pragma unroll
            for (int u = 0; u < 8; ++u)
                r[u] = ((const uint4*)(xin +
                          (size_t)(ev[u].x & 0x3FFFF) * 32))[l];
#pragma unroll
            for (int u = 0; u < 8; ++u) {
                int j = jb + u;
                float vw = (j < e) ? __int_as_float(ev[u].y) : 0.f;
                a0 += vw * unpack_bf16x2(r[u].x);
                a1 += vw * unpack_bf16x2(r[u].y);
                a2 += vw * unpack_bf16x2(r[u].z);
                a3 += vw * unpack_bf16x2(r[u].w);
            }
        }
        if (live) {
            uint4 o;
            o.x = pack_bf16(a0.x, a0.y);
            o.y = pack_bf16(a1.x, a1.y);
            o.z = pack_bf16(a2.x, a2.y);
            o.w = pack_bf16(a3.x, a3.y);
            ((uint4*)(xout + (size_t)(nodes0 + dl) * 32))[l] = o;
        }
    }
}

// SpMM over bf16 rows (128B/row). R16 form: 8 nodes per wave, one octet
// (8 lanes x uint4 = full row) per node. Per round: octet cooperatively
// loads 8 epair entries (64B coalesced), shfl-broadcasts src/val, issues
// 8 independent row gathers, then FMAs. No cross-lane reduce; wave
// stores 1KB contiguous (8 rows).
__global__ __launch_bounds__(256) void spmm_kernel(
        const uint* __restrict__ rowinfo, const int2* __restrict__ epair,
        const uint* __restrict__ xin, uint* __restrict__ xout) {
    int wave = (blockIdx.x * 256 + threadIdx.x) >> 6;
    int lane = threadIdx.x & 63;
    int g = lane >> 3;                // octet id = node slot 0..7
    int l = lane & 7;                 // uint4 slot within row
    int n = wave * 8 + g;
    bool live = n < N_NODES;
    uint ri = live ? rowinfo[n] : 0u;
    int s = (int)(ri & 0x3FFFFFu);
    int e = live ? s + (int)(ri >> 22) : s;   // empty/dead: e==s skips loop
    int gbase = g * 8;
    v2f a0 = {0.f, 0.f}, a1 = {0.f, 0.f}, a2 = {0.f, 0.f}, a3 = {0.f, 0.f};
    for (int jb = s; jb < e; jb += 8) {
        int jl = jb + l;
        // cooperative 64B epair fetch; tail clamps to e-1 (same line, w=0)
        int2 ev = epair[jl < e ? jl : (e - 1)];
        float vw = (jl < e) ? __int_as_float(ev.y) : 0.f;
        int sx = ev.x;
        int srcs[8];
        float ws[8];
#pragma unroll
        for (int u = 0; u < 8; ++u) {
            srcs[u] = __shfl(sx, gbase + u, 64);
            ws[u]   = __shfl(vw, gbase + u, 64);
        }
        uint4 r[8];
#pragma unroll
        for (int u = 0; u < 8; ++u)
            r[u] = ((const uint4*)(xin + (size_t)srcs[u] * 32))[l];
#pragma unroll
        for (int u = 0; u < 8; ++u) {
            a0 += ws[u] * unpack_bf16x2(r[u].x);
            a1 += ws[u] * unpack_bf16x2(r[u].y);
            a2 += ws[u] * unpack_bf16x2(r[u].z);
            a3 += ws[u] * unpack_bf16x2(r[u].w);
        }
    }
    if (live) {
        uint4 o;
        o.x = pack_bf16(a0.x, a0.y);
        o.y = pack_bf16(a1.x, a1.y);
        o.z = pack_bf16(a2.x, a2.y);
        o.w = pack_bf16(a3.x, a3.y);
        ((uint4*)(xout + (size_t)n * 32))[l] = o;   // wave: 8 rows = 1KB contig
    }
}

// Layer 3 + dot, fused: one wave per (user,item) pair. Half-wave per
// node (lanes 0-31 user, 32-63 item); within a half, 2 edge-groups x 16
// lanes; each lane owns dims 4l..4l+3 (uint2 slot l). After the x3
// gather: reduce across edge-groups (xor 16), add x0+x1+x2, cross-half
// shfl_xor(32) brings the partner row, in-wave dot, lane 0 writes gamma.
__global__ __launch_bounds__(256) void batch_dot_kernel(
        const int* __restrict__ users, const int* __restrict__ items,
        const float* __restrict__ emb_user, const float* __restrict__ emb_item,
        const uint* __restrict__ x1, const uint* __restrict__ x2,
        const uint* __restrict__ rowinfo, const int2* __restrict__ epair,
        float* __restrict__ out) {
    int b = (blockIdx.x * 256 + threadIdx.x) >> 6;   // 0..BATCH-1
    int lane = threadIdx.x & 63;
    int hg = (lane >> 4) & 1;  // edge-group within half
    int l = lane & 15;         // uint2 slot: dims 4l..4l+3
    bool isU = lane < 32;
    int idx = isU ? users[b] : items[b];
    int n = isU ? idx : N_USERS + idx;
    uint ri = rowinfo[n];
    int s = (int)(ri & 0x3FFFFFu);
    int e = s + (int)(ri >> 22);
    v2f a0 = {0.f, 0.f}, a1 = {0.f, 0.f};
    for (int j0 = s + hg; j0 < e; j0 += 8) {
        int2 ev[4];
        float vv[4];
        uint2 rr[4];
#pragma unroll
        for (int u = 0; u < 4; ++u) {
            int j = j0 + 2 * u;
            bool p = (u == 0) || (j < e);
            ev[u] = epair[p ? j : j0];
            vv[u] = p ? __int_as_float(ev[u].y) : 0.f;
        }
#pragma unroll
        for (int u = 0; u < 4; ++u)
            rr[u] = ((const uint2*)(x2 + (size_t)ev[u].x * 32))[l];
#pragma unroll
        for (int u = 0; u < 4; ++u) {
            a0 += vv[u] * unpack_bf16x2(rr[u].x);
            a1 += vv[u] * unpack_bf16x2(rr[u].y);
        }
    }
    // reduce across the 2 edge-groups (stays within each half)
    a0.x += __shfl_xor(a0.x, 16, 64);
    a0.y += __shfl_xor(a0.y, 16, 64);
    a1.x += __shfl_xor(a1.x, 16, 64);
    a1.y += __shfl_xor(a1.y, 16, 64);
    // epilogue: r = x0 + x1 + x2 + x3 for this node's dims 4l..4l+3
    const float* t0row = isU ? (emb_user + (size_t)idx * DIM)
                             : (emb_item + (size_t)idx * DIM);
    float4 x0 = ((const float4*)t0row)[l];
    uint2 w1 = ((const uint2*)(x1 + (size_t)n * 32))[l];
    uint2 w2 = ((const uint2*)(x2 + (size_t)n * 32))[l];
    v2f b10 = unpack_bf16x2(w1.x), b11 = unpack_bf16x2(w1.y);
    v2f b20 = unpack_bf16x2(w2.x), b21 = unpack_bf16x2(w2.y);
    float rx = x0.x + b10.x + b20.x + a0.x;
    float ry = x0.y + b10.y + b20.y + a0.y;
    float rz = x0.z + b11.x + b21.x + a1.x;
    float rw = x0.w + b11.y + b21.y + a1.y;
    // cross-half: partner row's same dims
    float ox = __shfl_xor(rx, 32, 64);
    float oy = __shfl_xor(ry, 32, 64);
    float oz = __shfl_xor(rz, 32, 64);
    float ow = __shfl_xor(rw, 32, 64);
    float p = rx * ox + ry * oy + rz * oz + rw * ow;
#pragma unroll
    for (int o = 1; o < 16; o <<= 1) p += __shfl_xor(p, o, 64);
    if (lane == 0) out[b] = p * (1.0f / 16.0f);
}

extern "C" void kernel_launch(void* const* d_in, const int* in_sizes, int n_in,
                              void* d_out, int out_size, void* d_ws, size_t ws_size,
                              hipStream_t stream) {
    const float* emb_user = (const float*)d_in[0];
    const float* emb_item = (const float*)d_in[1];
    const float* vals     = (const float*)d_in[2];
    const int*   src      = (const int*)d_in[3];
    const int*   dst      = (const int*)d_in[4];
    const int*   users    = (const int*)d_in[5];
    const int*   items    = (const int*)d_in[6];
    float* out = (float*)d_out;

    char* ws = (char*)d_ws;
    size_t off = 0;
    auto walloc = [&](size_t bytes) -> void* {
        void* p = ws + off;
        off += (bytes + 255) & ~(size_t)255;
        return p;
    };
    const size_t ROWB = (size_t)N_NODES * DIM * 2;                  // 19.2 MB
    uint* t0          = (uint*)walloc(ROWB);                        // bf16 x0
    uint* x1          = (uint*)walloc(ROWB);
    uint* x2          = (uint*)walloc(ROWB);
    int2* coarse      = (int2*)walloc((size_t)KB * ECAP * 8);       // 21.0 MB
    int*  gcur        = (int*) walloc((size_t)KB * GSTR * 4);       // padded
    uint* rowinfo     = (uint*)walloc((size_t)N_NODES * 4);

    hipMemsetAsync(gcur, 0, (size_t)KB * GSTR * 4, stream);

    // Build: partition sort (+ per-block conv tail slice), then
    // fused fine-sort + layer-1 spmm
    part_kernel<<<CHUNKS, 1024, 0, stream>>>(
        src, dst, vals, gcur, coarse, emb_user, emb_item, (uint2*)t0);
    p4f_spmm<<<KB, 1024, 0, stream>>>(coarse, gcur, rowinfo, t0, x1);

    // Layer 2 full; layer 3 + dot fused, batch-only
    const int SPMM_BLOCKS = (N_NODES / 8 * 64 + 255) / 256;
    spmm_kernel<<<SPMM_BLOCKS, 256, 0, stream>>>(rowinfo, coarse, x1, x2);
    batch_dot_kernel<<<(BATCH * 64) / 256, 256, 0, stream>>>(
        users, items, emb_user, emb_item, x1, x2, rowinfo, coarse, out);
}